// Round 1
// baseline (396.337 us; speedup 1.0000x reference)
//
#include <hip/hip_runtime.h>
#include <math.h>

#define N_ 8192
#define D_ 512
#define NC_ 128

typedef __attribute__((ext_vector_type(8))) short bf16x8;
typedef __attribute__((ext_vector_type(4))) float f32x4;
typedef __attribute__((ext_vector_type(4))) unsigned short us4;

static __device__ __forceinline__ unsigned short f2bf(float f) {
    union { float f; unsigned u; } c; c.f = f;
    unsigned u = c.u;
    u += 0x7fffu + ((u >> 16) & 1u);   // round-to-nearest-even
    return (unsigned short)(u >> 16);
}

// ---------- kernel 1: fp32 -> bf16 ----------
__global__ __launch_bounds__(256) void k_convert(const float* __restrict__ x,
                                                 unsigned short* __restrict__ xb) {
    int i = (blockIdx.x * 256 + threadIdx.x);
    float4 v = reinterpret_cast<const float4*>(x)[i];
    us4 o = { f2bf(v.x), f2bf(v.y), f2bf(v.z), f2bf(v.w) };
    reinterpret_cast<us4*>(xb)[i] = o;
}

// ---------- kernel 2: class histogram ----------
__global__ __launch_bounds__(256) void k_hist(const int* __restrict__ tg,
                                              int* __restrict__ hist) {
    __shared__ int lh[NC_];
    if (threadIdx.x < NC_) lh[threadIdx.x] = 0;
    __syncthreads();
    int i = blockIdx.x * 256 + threadIdx.x;
    atomicAdd(&lh[tg[i]], 1);
    __syncthreads();
    if (threadIdx.x < NC_ && lh[threadIdx.x] != 0) atomicAdd(&hist[threadIdx.x], lh[threadIdx.x]);
}

// ---------- kernel 3: fused bf16 MFMA sim + masked exp row sums ----------
// grid = 64 row-tiles * 8 col-groups = 512 blocks, 256 threads (4 waves, 2x2)
// block tile: 128 rows x (8 x 128) cols, K staged in BK=64 chunks
__global__ __launch_bounds__(256) void k_main(const unsigned short* __restrict__ xb,
                                              const int* __restrict__ tg,
                                              float* __restrict__ psum,
                                              float* __restrict__ nsum) {
    __shared__ alignas(16) unsigned short As[128 * 64];
    __shared__ alignas(16) unsigned short Bs[128 * 64];
    __shared__ int rowT[128];

    const int tid  = threadIdx.x;
    const int w    = tid >> 6;
    const int lane = tid & 63;
    const int q    = lane >> 4;
    const int l15  = lane & 15;
    const int wrow = w >> 1;      // 0..1
    const int wcol = w & 1;       // 0..1
    const int rt   = blockIdx.x >> 3;  // 0..63
    const int cg   = blockIdx.x & 7;   // 0..7
    const int row0 = rt * 128;

    if (tid < 128) rowT[tid] = tg[row0 + tid];
    __syncthreads();

    int tR[4][4];
#pragma unroll
    for (int mi = 0; mi < 4; ++mi)
#pragma unroll
        for (int r = 0; r < 4; ++r)
            tR[mi][r] = rowT[wrow * 64 + mi * 16 + q * 4 + r];

    float ps[4][4];
    float ns[4][4];
#pragma unroll
    for (int mi = 0; mi < 4; ++mi)
#pragma unroll
        for (int r = 0; r < 4; ++r) { ps[mi][r] = 0.f; ns[mi][r] = 0.f; }

    for (int ct = 0; ct < 8; ++ct) {
        const int col0 = cg * 1024 + ct * 128;
        int tC[4];
#pragma unroll
        for (int ni = 0; ni < 4; ++ni)
            tC[ni] = tg[col0 + wcol * 64 + ni * 16 + l15];

        f32x4 acc[4][4];
#pragma unroll
        for (int mi = 0; mi < 4; ++mi)
#pragma unroll
            for (int ni = 0; ni < 4; ++ni)
                acc[mi][ni] = (f32x4){0.f, 0.f, 0.f, 0.f};

        for (int ks = 0; ks < 8; ++ks) {
            const int k0 = ks * 64;
            __syncthreads();   // prior ds_reads done before restaging
            // stage A(128x64) and B(128x64): 4 wave-issues each, 16B/lane,
            // XOR-swizzled source so LDS slot s holds kgroup g = s ^ (row&7)
#pragma unroll
            for (int it = 0; it < 4; ++it) {
                int gs = (it * 4 + w) * 64 + lane;
                int r  = gs >> 3;
                int s  = gs & 7;
                int g  = s ^ (r & 7);
                const unsigned short* ga = xb + (size_t)(row0 + r) * D_ + k0 + g * 8;
                const unsigned short* gb = xb + (size_t)(col0 + r) * D_ + k0 + g * 8;
                __builtin_amdgcn_global_load_lds(
                    (const __attribute__((address_space(1))) void*)ga,
                    (__attribute__((address_space(3))) void*)(As + (it * 4 + w) * 512),
                    16, 0, 0);
                __builtin_amdgcn_global_load_lds(
                    (const __attribute__((address_space(1))) void*)gb,
                    (__attribute__((address_space(3))) void*)(Bs + (it * 4 + w) * 512),
                    16, 0, 0);
            }
            __syncthreads();   // barrier drains vmcnt -> LDS valid

#pragma unroll
            for (int kc = 0; kc < 2; ++kc) {
                bf16x8 aF[4], bF[4];
#pragma unroll
                for (int mi = 0; mi < 4; ++mi) {
                    int rA = wrow * 64 + mi * 16 + l15;
                    int g  = kc * 4 + q;
                    int s  = g ^ (rA & 7);
                    aF[mi] = *reinterpret_cast<const bf16x8*>(As + rA * 64 + s * 8);
                }
#pragma unroll
                for (int ni = 0; ni < 4; ++ni) {
                    int rB = wcol * 64 + ni * 16 + l15;
                    int g  = kc * 4 + q;
                    int s  = g ^ (rB & 7);
                    bF[ni] = *reinterpret_cast<const bf16x8*>(Bs + rB * 64 + s * 8);
                }
#pragma unroll
                for (int mi = 0; mi < 4; ++mi)
#pragma unroll
                    for (int ni = 0; ni < 4; ++ni)
                        acc[mi][ni] = __builtin_amdgcn_mfma_f32_16x16x32_bf16(
                            aF[mi], bF[ni], acc[mi][ni], 0, 0, 0);
            }
        }

        // epilogue: mask + exp, accumulate per-row partials in registers
#pragma unroll
        for (int mi = 0; mi < 4; ++mi)
#pragma unroll
            for (int ni = 0; ni < 4; ++ni)
#pragma unroll
                for (int r = 0; r < 4; ++r) {
                    float s = acc[mi][ni][r];
                    bool same = (tR[mi][r] == tC[ni]);
                    float ep = __expf(1.0f - s);
                    float en = __expf(s);
                    if (same) { if (s < 1.0f) ps[mi][r] += ep; }
                    else       ns[mi][r] += en;
                }
    }

    // reduce across the 16 lanes sharing a row (xor over l15), then atomics
#pragma unroll
    for (int mi = 0; mi < 4; ++mi)
#pragma unroll
        for (int r = 0; r < 4; ++r) {
            float p = ps[mi][r];
            float n = ns[mi][r];
#pragma unroll
            for (int m = 1; m < 16; m <<= 1) {
                p += __shfl_xor(p, m, 64);
                n += __shfl_xor(n, m, 64);
            }
            if (l15 == 0) {
                int R = row0 + wrow * 64 + mi * 16 + q * 4 + r;
                atomicAdd(&psum[R], p);
                atomicAdd(&nsum[R], n);
            }
        }
}

// ---------- kernel 4: exact fp64 last-row stats (one wave per column j) ----------
__global__ __launch_bounds__(256) void k_last(const float* __restrict__ x,
                                              const int* __restrict__ tg,
                                              double* lps, double* lns,
                                              int* lpc, int* lnc) {
    int j    = (blockIdx.x * 256 + threadIdx.x) >> 6;
    int lane = threadIdx.x & 63;
    const float* xl = x + (size_t)(N_ - 1) * D_;
    const float* xj = x + (size_t)j * D_;
    double acc = 0.0;
#pragma unroll
    for (int it = 0; it < 8; ++it) {
        int k = it * 64 + lane;
        acc += (double)xl[k] * (double)xj[k];
    }
#pragma unroll
    for (int m = 32; m >= 1; m >>= 1) acc += __shfl_xor(acc, m, 64);
    if (lane == 0) {
        bool same = (tg[j] == tg[N_ - 1]);
        if (same) {
            if (acc < 1.0) { atomicAdd(lps, acc); atomicAdd(lpc, 1); }
        } else {
            atomicAdd(lns, acc); atomicAdd(lnc, 1);
        }
    }
}

// ---------- kernel 5: finalize ----------
__global__ __launch_bounds__(256) void k_final(const float* __restrict__ psum,
                                               const float* __restrict__ nsum,
                                               const int* __restrict__ tg,
                                               const int* __restrict__ hist,
                                               const double* lps, const double* lns,
                                               const int* lpc, const int* lnc,
                                               float* __restrict__ out) {
    __shared__ double sd[256];
    __shared__ int    si[256];
    int tid = threadIdx.x;
    double part = 0.0;
    int skip = 0;
    for (int i = tid; i < N_; i += 256) {
        if (hist[tg[i]] < N_) {
            part += (double)(logf(psum[i]) + logf(nsum[i]));
        } else {
            skip++;
        }
    }
    sd[tid] = part; si[tid] = skip;
    __syncthreads();
    for (int s = 128; s >= 1; s >>= 1) {
        if (tid < s) { sd[tid] += sd[tid + s]; si[tid] += si[tid + s]; }
        __syncthreads();
    }
    if (tid == 0) {
        out[0] = (float)(sd[0] / (double)N_);
        out[1] = (float)si[0] / (float)N_;
        out[2] = (float)(*lps / (double)(*lpc));
        out[3] = (float)(*lns / (double)(*lnc));
    }
}

extern "C" void kernel_launch(void* const* d_in, const int* in_sizes, int n_in,
                              void* d_out, int out_size, void* d_ws, size_t ws_size,
                              hipStream_t stream) {
    const float* x  = (const float*)d_in[0];
    const int*   tg = (const int*)d_in[1];
    char* ws = (char*)d_ws;

    unsigned short* xb = (unsigned short*)ws;            // 8192*512*2 = 8 MB
    const size_t XB = (size_t)N_ * D_ * 2;               // 8388608
    float* psum = (float*)(ws + XB);                     // 32 KB
    float* nsum = (float*)(ws + XB + 32768);             // 32 KB
    int*   hist = (int*)(ws + XB + 65536);               // 512 B
    char*  lb   = ws + XB + 65536 + 512;
    double* lps = (double*)lb;
    double* lns = (double*)(lb + 8);
    int*    lpc = (int*)(lb + 16);
    int*    lnc = (int*)(lb + 20);

    // zero accumulators (ws is poisoned before every launch)
    hipMemsetAsync(ws + XB, 0, 65536 + 512 + 32, stream);

    hipLaunchKernelGGL(k_convert, dim3((N_ * D_) / (256 * 4)), dim3(256), 0, stream, x, xb);
    hipLaunchKernelGGL(k_hist, dim3(N_ / 256), dim3(256), 0, stream, tg, hist);
    hipLaunchKernelGGL(k_main, dim3(512), dim3(256), 0, stream, xb, tg, psum, nsum);
    hipLaunchKernelGGL(k_last, dim3((N_ * 64) / 256), dim3(256), 0, stream, x, tg, lps, lns, lpc, lnc);
    hipLaunchKernelGGL(k_final, dim3(1), dim3(256), 0, stream,
                       psum, nsum, tg, hist, lps, lns, lpc, lnc, (float*)d_out);
}

// Round 2
// 215.533 us; speedup vs baseline: 1.8389x; 1.8389x over previous
//
#include <hip/hip_runtime.h>
#include <math.h>

#define N_ 8192
#define D_ 512
#define NC_ 128

typedef __attribute__((ext_vector_type(8))) short bf16x8;
typedef __attribute__((ext_vector_type(4))) float f32x4;
typedef __attribute__((ext_vector_type(4))) unsigned short us4;

static __device__ __forceinline__ unsigned short f2bf(float f) {
    union { float f; unsigned u; } c; c.f = f;
    unsigned u = c.u;
    u += 0x7fffu + ((u >> 16) & 1u);   // round-to-nearest-even
    return (unsigned short)(u >> 16);
}

// ---------- kernel 1: fp32 -> bf16 ----------
__global__ __launch_bounds__(256) void k_convert(const float* __restrict__ x,
                                                 unsigned short* __restrict__ xb) {
    int i = (blockIdx.x * 256 + threadIdx.x);
    float4 v = reinterpret_cast<const float4*>(x)[i];
    us4 o = { f2bf(v.x), f2bf(v.y), f2bf(v.z), f2bf(v.w) };
    reinterpret_cast<us4*>(xb)[i] = o;
}

// ---------- kernel 2: class histogram ----------
__global__ __launch_bounds__(256) void k_hist(const int* __restrict__ tg,
                                              int* __restrict__ hist) {
    __shared__ int lh[NC_];
    if (threadIdx.x < NC_) lh[threadIdx.x] = 0;
    __syncthreads();
    int i = blockIdx.x * 256 + threadIdx.x;
    atomicAdd(&lh[tg[i]], 1);
    __syncthreads();
    if (threadIdx.x < NC_ && lh[threadIdx.x] != 0) atomicAdd(&hist[threadIdx.x], lh[threadIdx.x]);
}

// ---------- kernel 3: fused bf16 MFMA sim + masked exp row sums ----------
// grid = 64 row-tiles * 8 col-groups = 512 blocks, 256 threads (4 waves, 2x2)
// block tile: 128 rows x (8 x 128) cols, K staged in BK=64 chunks
__global__ __launch_bounds__(256) void k_main(const unsigned short* __restrict__ xb,
                                              const int* __restrict__ tg,
                                              float* __restrict__ psum,
                                              float* __restrict__ nsum) {
    __shared__ alignas(16) unsigned short As[128 * 64];
    __shared__ alignas(16) unsigned short Bs[128 * 64];
    __shared__ int rowT[128];

    const int tid  = threadIdx.x;
    const int w    = tid >> 6;
    const int lane = tid & 63;
    const int q    = lane >> 4;
    const int l15  = lane & 15;
    const int wrow = w >> 1;      // 0..1
    const int wcol = w & 1;       // 0..1
    const int rt   = blockIdx.x >> 3;  // 0..63
    const int cg   = blockIdx.x & 7;   // 0..7
    const int row0 = rt * 128;

    if (tid < 128) rowT[tid] = tg[row0 + tid];
    __syncthreads();

    int tR[4][4];
#pragma unroll
    for (int mi = 0; mi < 4; ++mi)
#pragma unroll
        for (int r = 0; r < 4; ++r)
            tR[mi][r] = rowT[wrow * 64 + mi * 16 + q * 4 + r];

    float ps[4][4];
    float ns[4][4];
#pragma unroll
    for (int mi = 0; mi < 4; ++mi)
#pragma unroll
        for (int r = 0; r < 4; ++r) { ps[mi][r] = 0.f; ns[mi][r] = 0.f; }

    for (int ct = 0; ct < 8; ++ct) {
        const int col0 = cg * 1024 + ct * 128;
        int tC[4];
#pragma unroll
        for (int ni = 0; ni < 4; ++ni)
            tC[ni] = tg[col0 + wcol * 64 + ni * 16 + l15];

        f32x4 acc[4][4];
#pragma unroll
        for (int mi = 0; mi < 4; ++mi)
#pragma unroll
            for (int ni = 0; ni < 4; ++ni)
                acc[mi][ni] = (f32x4){0.f, 0.f, 0.f, 0.f};

        for (int ks = 0; ks < 8; ++ks) {
            const int k0 = ks * 64;
            __syncthreads();   // prior ds_reads done before restaging
            // stage A(128x64) and B(128x64): 4 wave-issues each, 16B/lane,
            // XOR-swizzled source so LDS slot s holds kgroup g = s ^ (row&7)
#pragma unroll
            for (int it = 0; it < 4; ++it) {
                int gs = (it * 4 + w) * 64 + lane;
                int r  = gs >> 3;
                int s  = gs & 7;
                int g  = s ^ (r & 7);
                const unsigned short* ga = xb + (size_t)(row0 + r) * D_ + k0 + g * 8;
                const unsigned short* gb = xb + (size_t)(col0 + r) * D_ + k0 + g * 8;
                __builtin_amdgcn_global_load_lds(
                    (const __attribute__((address_space(1))) void*)ga,
                    (__attribute__((address_space(3))) void*)(As + (it * 4 + w) * 512),
                    16, 0, 0);
                __builtin_amdgcn_global_load_lds(
                    (const __attribute__((address_space(1))) void*)gb,
                    (__attribute__((address_space(3))) void*)(Bs + (it * 4 + w) * 512),
                    16, 0, 0);
            }
            __syncthreads();   // barrier drains vmcnt -> LDS valid

#pragma unroll
            for (int kc = 0; kc < 2; ++kc) {
                bf16x8 aF[4], bF[4];
#pragma unroll
                for (int mi = 0; mi < 4; ++mi) {
                    int rA = wrow * 64 + mi * 16 + l15;
                    int g  = kc * 4 + q;
                    int s  = g ^ (rA & 7);
                    aF[mi] = *reinterpret_cast<const bf16x8*>(As + rA * 64 + s * 8);
                }
#pragma unroll
                for (int ni = 0; ni < 4; ++ni) {
                    int rB = wcol * 64 + ni * 16 + l15;
                    int g  = kc * 4 + q;
                    int s  = g ^ (rB & 7);
                    bF[ni] = *reinterpret_cast<const bf16x8*>(Bs + rB * 64 + s * 8);
                }
#pragma unroll
                for (int mi = 0; mi < 4; ++mi)
#pragma unroll
                    for (int ni = 0; ni < 4; ++ni)
                        acc[mi][ni] = __builtin_amdgcn_mfma_f32_16x16x32_bf16(
                            aF[mi], bF[ni], acc[mi][ni], 0, 0, 0);
            }
        }

        // epilogue: mask + exp, accumulate per-row partials in registers
#pragma unroll
        for (int mi = 0; mi < 4; ++mi)
#pragma unroll
            for (int ni = 0; ni < 4; ++ni)
#pragma unroll
                for (int r = 0; r < 4; ++r) {
                    float s = acc[mi][ni][r];
                    bool same = (tR[mi][r] == tC[ni]);
                    float ep = __expf(1.0f - s);
                    float en = __expf(s);
                    if (same) { if (s < 1.0f) ps[mi][r] += ep; }
                    else       ns[mi][r] += en;
                }
    }

    // reduce across the 16 lanes sharing a row (xor over l15), then atomics
#pragma unroll
    for (int mi = 0; mi < 4; ++mi)
#pragma unroll
        for (int r = 0; r < 4; ++r) {
            float p = ps[mi][r];
            float n = ns[mi][r];
#pragma unroll
            for (int m = 1; m < 16; m <<= 1) {
                p += __shfl_xor(p, m, 64);
                n += __shfl_xor(n, m, 64);
            }
            if (l15 == 0) {
                int R = row0 + wrow * 64 + mi * 16 + q * 4 + r;
                atomicAdd(&psum[R], p);
                atomicAdd(&nsum[R], n);
            }
        }
}

// ---------- kernel 4: exact fp64 last-row dots -> sim_last[j] (no atomics) ----------
__global__ __launch_bounds__(256) void k_last(const float* __restrict__ x,
                                              double* __restrict__ sim_last) {
    int j    = (blockIdx.x * 256 + threadIdx.x) >> 6;
    int lane = threadIdx.x & 63;
    const float* xl = x + (size_t)(N_ - 1) * D_;
    const float* xj = x + (size_t)j * D_;
    double acc = 0.0;
#pragma unroll
    for (int it = 0; it < 8; ++it) {
        int k = it * 64 + lane;
        acc += (double)xl[k] * (double)xj[k];
    }
#pragma unroll
    for (int m = 32; m >= 1; m >>= 1) acc += __shfl_xor(acc, m, 64);
    if (lane == 0) sim_last[j] = acc;
}

// ---------- kernel 5: finalize (single block, fp64 reductions) ----------
__global__ __launch_bounds__(256) void k_final(const float* __restrict__ psum,
                                               const float* __restrict__ nsum,
                                               const int* __restrict__ tg,
                                               const int* __restrict__ hist,
                                               const double* __restrict__ sim_last,
                                               float* __restrict__ out) {
    __shared__ double sl[256], sp[256], sn[256];
    __shared__ int    sk[256], cp[256], cn[256];
    int tid = threadIdx.x;

    // loss + prec
    double part = 0.0;
    int skip = 0;
    for (int i = tid; i < N_; i += 256) {
        if (hist[tg[i]] < N_) {
            part += (double)(logf(psum[i]) + logf(nsum[i]));
        } else {
            skip++;
        }
    }

    // last-row stats from sim_last
    double pd = 0.0, nd = 0.0;
    int pc = 0, nc = 0;
    int tlast = tg[N_ - 1];
    for (int j = tid; j < N_; j += 256) {
        double s = sim_last[j];
        if (tg[j] == tlast) {
            if (s < 1.0) { pd += s; pc++; }
        } else {
            nd += s; nc++;
        }
    }

    sl[tid] = part; sk[tid] = skip;
    sp[tid] = pd;   cp[tid] = pc;
    sn[tid] = nd;   cn[tid] = nc;
    __syncthreads();
    for (int s = 128; s >= 1; s >>= 1) {
        if (tid < s) {
            sl[tid] += sl[tid + s]; sk[tid] += sk[tid + s];
            sp[tid] += sp[tid + s]; cp[tid] += cp[tid + s];
            sn[tid] += sn[tid + s]; cn[tid] += cn[tid + s];
        }
        __syncthreads();
    }
    if (tid == 0) {
        out[0] = (float)(sl[0] / (double)N_);
        out[1] = (float)sk[0] / (float)N_;
        out[2] = (float)(sp[0] / (double)cp[0]);
        out[3] = (float)(sn[0] / (double)cn[0]);
    }
}

extern "C" void kernel_launch(void* const* d_in, const int* in_sizes, int n_in,
                              void* d_out, int out_size, void* d_ws, size_t ws_size,
                              hipStream_t stream) {
    const float* x  = (const float*)d_in[0];
    const int*   tg = (const int*)d_in[1];
    char* ws = (char*)d_ws;

    unsigned short* xb = (unsigned short*)ws;            // 8192*512*2 = 8 MB
    const size_t XB = (size_t)N_ * D_ * 2;               // 8388608
    float*  psum     = (float*)(ws + XB);                // 32 KB
    float*  nsum     = (float*)(ws + XB + 32768);        // 32 KB
    int*    hist     = (int*)(ws + XB + 65536);          // 512 B
    double* sim_last = (double*)(ws + XB + 65536 + 512); // 64 KB

    // zero accumulators (ws is poisoned before every launch)
    hipMemsetAsync(ws + XB, 0, 65536 + 512, stream);

    hipLaunchKernelGGL(k_convert, dim3((N_ * D_) / (256 * 4)), dim3(256), 0, stream, x, xb);
    hipLaunchKernelGGL(k_hist, dim3(N_ / 256), dim3(256), 0, stream, tg, hist);
    hipLaunchKernelGGL(k_main, dim3(512), dim3(256), 0, stream, xb, tg, psum, nsum);
    hipLaunchKernelGGL(k_last, dim3((N_ * 64) / 256), dim3(256), 0, stream, x, sim_last);
    hipLaunchKernelGGL(k_final, dim3(1), dim3(256), 0, stream,
                       psum, nsum, tg, hist, sim_last, (float*)d_out);
}

// Round 3
// 213.824 us; speedup vs baseline: 1.8536x; 1.0080x over previous
//
#include <hip/hip_runtime.h>
#include <math.h>

#define N_ 8192
#define D_ 512
#define NC_ 128
#define T_ 64   // 8192/128 row-tiles

typedef __attribute__((ext_vector_type(8))) short bf16x8;
typedef __attribute__((ext_vector_type(4))) float f32x4;
typedef __attribute__((ext_vector_type(4))) unsigned short us4;

static __device__ __forceinline__ unsigned short f2bf(float f) {
    union { float f; unsigned u; } c; c.f = f;
    unsigned u = c.u;
    u += 0x7fffu + ((u >> 16) & 1u);   // round-to-nearest-even
    return (unsigned short)(u >> 16);
}

// ---------- kernel 1: fp32 -> bf16, also zero psum/nsum (blocks 0..15) ----------
__global__ __launch_bounds__(256) void k_convert(const float* __restrict__ x,
                                                 unsigned short* __restrict__ xb,
                                                 float* __restrict__ accbuf) {
    int i = (blockIdx.x * 256 + threadIdx.x);
    if (blockIdx.x < 16) {
        // zero 16384 floats (psum 8192 + nsum 8192, contiguous)
        reinterpret_cast<float4*>(accbuf)[i] = make_float4(0.f, 0.f, 0.f, 0.f);
    }
    float4 v = reinterpret_cast<const float4*>(x)[i];
    us4 o = { f2bf(v.x), f2bf(v.y), f2bf(v.z), f2bf(v.w) };
    reinterpret_cast<us4*>(xb)[i] = o;
}

// ---------- kernel 2: symmetric fused bf16 MFMA sim + masked exp row/col sums ----
// grid = 2080 triangular tile-pairs (it<=jt), 128x128 tile, 256 threads (2x2 waves)
// Off-diagonal tiles scatter exp partials to BOTH row sums (I) and col sums (J);
// exp values are bit-identical to the full-matrix version (same MFMA operands).
__global__ __launch_bounds__(256, 4) void k_main(const unsigned short* __restrict__ xb,
                                                 const int* __restrict__ tg,
                                                 float* __restrict__ psum,
                                                 float* __restrict__ nsum) {
    __shared__ alignas(16) unsigned short As[128 * 64];
    __shared__ alignas(16) unsigned short Bs[128 * 64];
    __shared__ int rowT[128];

    const int tid  = threadIdx.x;
    const int w    = tid >> 6;
    const int lane = tid & 63;
    const int q    = lane >> 4;
    const int l15  = lane & 15;
    const int wrow = w >> 1;      // 0..1
    const int wcol = w & 1;       // 0..1

    // triangular decode: blockIdx.x -> (it, jt), it<=jt
    int rem = blockIdx.x;
    int it = 0;
    while (rem >= (T_ - it)) { rem -= (T_ - it); it++; }
    const int jt = it + rem;
    const int row0 = it * 128;
    const int col0 = jt * 128;

    if (tid < 128) rowT[tid] = tg[row0 + tid];
    __syncthreads();

    int tR[4][4];
#pragma unroll
    for (int mi = 0; mi < 4; ++mi)
#pragma unroll
        for (int r = 0; r < 4; ++r)
            tR[mi][r] = rowT[wrow * 64 + mi * 16 + q * 4 + r];

    int tC[4];
#pragma unroll
    for (int ni = 0; ni < 4; ++ni)
        tC[ni] = tg[col0 + wcol * 64 + ni * 16 + l15];

    f32x4 acc[4][4];
#pragma unroll
    for (int mi = 0; mi < 4; ++mi)
#pragma unroll
        for (int ni = 0; ni < 4; ++ni)
            acc[mi][ni] = (f32x4){0.f, 0.f, 0.f, 0.f};

    for (int ks = 0; ks < 8; ++ks) {
        const int k0 = ks * 64;
        __syncthreads();   // prior ds_reads done before restaging
        // stage A(128x64) and B(128x64): 4 wave-issues each, 16B/lane,
        // XOR-swizzled source so LDS slot s holds kgroup g = s ^ (row&7)
#pragma unroll
        for (int itr = 0; itr < 4; ++itr) {
            int gs = (itr * 4 + w) * 64 + lane;
            int r  = gs >> 3;
            int s  = gs & 7;
            int g  = s ^ (r & 7);
            const unsigned short* ga = xb + (size_t)(row0 + r) * D_ + k0 + g * 8;
            const unsigned short* gb = xb + (size_t)(col0 + r) * D_ + k0 + g * 8;
            __builtin_amdgcn_global_load_lds(
                (const __attribute__((address_space(1))) void*)ga,
                (__attribute__((address_space(3))) void*)(As + (itr * 4 + w) * 512),
                16, 0, 0);
            __builtin_amdgcn_global_load_lds(
                (const __attribute__((address_space(1))) void*)gb,
                (__attribute__((address_space(3))) void*)(Bs + (itr * 4 + w) * 512),
                16, 0, 0);
        }
        __syncthreads();   // barrier drains vmcnt -> LDS valid

#pragma unroll
        for (int kc = 0; kc < 2; ++kc) {
            bf16x8 aF[4], bF[4];
#pragma unroll
            for (int mi = 0; mi < 4; ++mi) {
                int rA = wrow * 64 + mi * 16 + l15;
                int g  = kc * 4 + q;
                int s  = g ^ (rA & 7);
                aF[mi] = *reinterpret_cast<const bf16x8*>(As + rA * 64 + s * 8);
            }
#pragma unroll
            for (int ni = 0; ni < 4; ++ni) {
                int rB = wcol * 64 + ni * 16 + l15;
                int g  = kc * 4 + q;
                int s  = g ^ (rB & 7);
                bF[ni] = *reinterpret_cast<const bf16x8*>(Bs + rB * 64 + s * 8);
            }
#pragma unroll
            for (int mi = 0; mi < 4; ++mi)
#pragma unroll
                for (int ni = 0; ni < 4; ++ni)
                    acc[mi][ni] = __builtin_amdgcn_mfma_f32_16x16x32_bf16(
                        aF[mi], bF[ni], acc[mi][ni], 0, 0, 0);
        }
    }

    // epilogue: single exp per element; accumulate row partials and (off-diag)
    // column partials from the SAME exp values (sim symmetric, bit-identical)
    float ps[4][4], ns[4][4];
    float cps[4], cns[4];
#pragma unroll
    for (int mi = 0; mi < 4; ++mi)
#pragma unroll
        for (int r = 0; r < 4; ++r) { ps[mi][r] = 0.f; ns[mi][r] = 0.f; }
#pragma unroll
    for (int ni = 0; ni < 4; ++ni) { cps[ni] = 0.f; cns[ni] = 0.f; }

#pragma unroll
    for (int mi = 0; mi < 4; ++mi)
#pragma unroll
        for (int ni = 0; ni < 4; ++ni)
#pragma unroll
            for (int r = 0; r < 4; ++r) {
                float s = acc[mi][ni][r];
                bool same = (tR[mi][r] == tC[ni]);
                float e = __expf(same ? 1.0f - s : s);
                float pe = (same && (s < 1.0f)) ? e : 0.0f;
                float ne = same ? 0.0f : e;
                ps[mi][r] += pe; ns[mi][r] += ne;
                cps[ni]   += pe; cns[ni]   += ne;
            }

    // row reduction: sum across the 16 lanes sharing a row (xor over l15 bits)
#pragma unroll
    for (int mi = 0; mi < 4; ++mi)
#pragma unroll
        for (int r = 0; r < 4; ++r) {
            float p = ps[mi][r];
            float n = ns[mi][r];
#pragma unroll
            for (int m = 1; m < 16; m <<= 1) {
                p += __shfl_xor(p, m, 64);
                n += __shfl_xor(n, m, 64);
            }
            if (l15 == 0) {
                int R = row0 + wrow * 64 + mi * 16 + q * 4 + r;
                atomicAdd(&psum[R], p);
                atomicAdd(&nsum[R], n);
            }
        }

    // column reduction (off-diagonal only): sum across q (lane bits 16,32)
    if (jt != it) {
#pragma unroll
        for (int ni = 0; ni < 4; ++ni) {
            float p = cps[ni];
            float n = cns[ni];
            p += __shfl_xor(p, 16, 64); p += __shfl_xor(p, 32, 64);
            n += __shfl_xor(n, 16, 64); n += __shfl_xor(n, 32, 64);
            if (q == 0) {
                int C = col0 + wcol * 64 + ni * 16 + l15;
                atomicAdd(&psum[C], p);
                atomicAdd(&nsum[C], n);
            }
        }
    }
}

// ---------- kernel 3: exact fp64 last-row dots -> sim_last[j] (no atomics) ----------
__global__ __launch_bounds__(256) void k_last(const float* __restrict__ x,
                                              double* __restrict__ sim_last) {
    int j    = (blockIdx.x * 256 + threadIdx.x) >> 6;
    int lane = threadIdx.x & 63;
    const float* xl = x + (size_t)(N_ - 1) * D_;
    const float* xj = x + (size_t)j * D_;
    double acc = 0.0;
#pragma unroll
    for (int it = 0; it < 8; ++it) {
        int k = it * 64 + lane;
        acc += (double)xl[k] * (double)xj[k];
    }
#pragma unroll
    for (int m = 32; m >= 1; m >>= 1) acc += __shfl_xor(acc, m, 64);
    if (lane == 0) sim_last[j] = acc;
}

// ---------- kernel 4: finalize (single block; builds class hist in LDS) ----------
__global__ __launch_bounds__(256) void k_final(const float* __restrict__ psum,
                                               const float* __restrict__ nsum,
                                               const int* __restrict__ tg,
                                               const double* __restrict__ sim_last,
                                               float* __restrict__ out) {
    __shared__ int lh[NC_];
    __shared__ double sl[256], sp[256], sn[256];
    __shared__ int    sk[256], cp[256], cn[256];
    int tid = threadIdx.x;

    if (tid < NC_) lh[tid] = 0;
    __syncthreads();
    for (int i = tid; i < N_; i += 256) atomicAdd(&lh[tg[i]], 1);
    __syncthreads();

    // loss + prec
    double part = 0.0;
    int skip = 0;
    for (int i = tid; i < N_; i += 256) {
        if (lh[tg[i]] < N_) {
            part += (double)(logf(psum[i]) + logf(nsum[i]));
        } else {
            skip++;
        }
    }

    // last-row stats from sim_last
    double pd = 0.0, nd = 0.0;
    int pc = 0, nc = 0;
    int tlast = tg[N_ - 1];
    for (int j = tid; j < N_; j += 256) {
        double s = sim_last[j];
        if (tg[j] == tlast) {
            if (s < 1.0) { pd += s; pc++; }
        } else {
            nd += s; nc++;
        }
    }

    sl[tid] = part; sk[tid] = skip;
    sp[tid] = pd;   cp[tid] = pc;
    sn[tid] = nd;   cn[tid] = nc;
    __syncthreads();
    for (int s = 128; s >= 1; s >>= 1) {
        if (tid < s) {
            sl[tid] += sl[tid + s]; sk[tid] += sk[tid + s];
            sp[tid] += sp[tid + s]; cp[tid] += cp[tid + s];
            sn[tid] += sn[tid + s]; cn[tid] += cn[tid + s];
        }
        __syncthreads();
    }
    if (tid == 0) {
        out[0] = (float)(sl[0] / (double)N_);
        out[1] = (float)sk[0] / (float)N_;
        out[2] = (float)(sp[0] / (double)cp[0]);
        out[3] = (float)(sn[0] / (double)cn[0]);
    }
}

extern "C" void kernel_launch(void* const* d_in, const int* in_sizes, int n_in,
                              void* d_out, int out_size, void* d_ws, size_t ws_size,
                              hipStream_t stream) {
    const float* x  = (const float*)d_in[0];
    const int*   tg = (const int*)d_in[1];
    char* ws = (char*)d_ws;

    unsigned short* xb = (unsigned short*)ws;            // 8192*512*2 = 8 MB
    const size_t XB = (size_t)N_ * D_ * 2;               // 8388608
    float*  psum     = (float*)(ws + XB);                // 32 KB
    float*  nsum     = (float*)(ws + XB + 32768);        // 32 KB (contiguous w/ psum)
    double* sim_last = (double*)(ws + XB + 65536);       // 64 KB

    const int nblk_tri = T_ * (T_ + 1) / 2;              // 2080

    hipLaunchKernelGGL(k_convert, dim3((N_ * D_) / (256 * 4)), dim3(256), 0, stream,
                       x, xb, psum);
    hipLaunchKernelGGL(k_main, dim3(nblk_tri), dim3(256), 0, stream, xb, tg, psum, nsum);
    hipLaunchKernelGGL(k_last, dim3((N_ * 64) / 256), dim3(256), 0, stream, x, sim_last);
    hipLaunchKernelGGL(k_final, dim3(1), dim3(256), 0, stream,
                       psum, nsum, tg, sim_last, (float*)d_out);
}

// Round 4
// 166.078 us; speedup vs baseline: 2.3865x; 1.2875x over previous
//
#include <hip/hip_runtime.h>
#include <math.h>

#define N_ 8192
#define D_ 512
#define NC_ 128
#define T_ 64   // 8192/128 row-tiles

typedef __attribute__((ext_vector_type(8))) short bf16x8;
typedef __attribute__((ext_vector_type(4))) float f32x4;
typedef __attribute__((ext_vector_type(4))) unsigned short us4;

static __device__ __forceinline__ unsigned short f2bf(float f) {
    union { float f; unsigned u; } c; c.f = f;
    unsigned u = c.u;
    u += 0x7fffu + ((u >> 16) & 1u);   // round-to-nearest-even
    return (unsigned short)(u >> 16);
}

// ---------- kernel 1: fp32 -> bf16 ----------
__global__ __launch_bounds__(256) void k_convert(const float* __restrict__ x,
                                                 unsigned short* __restrict__ xb) {
    int i = (blockIdx.x * 256 + threadIdx.x);
    float4 v = reinterpret_cast<const float4*>(x)[i];
    us4 o = { f2bf(v.x), f2bf(v.y), f2bf(v.z), f2bf(v.w) };
    reinterpret_cast<us4*>(xb)[i] = o;
}

// ---------- kernel 2: symmetric fused bf16 MFMA sim + masked exp partials ----
// grid = 2080 triangular tile-pairs (it<=jt), 128x128 tile, 256 threads (2x2 waves).
// NO ATOMICS: block (a,b) writes row-partials to buf[a][b][0..127] and (a<b)
// col-partials to buf[b][a][0..127]; every slot written exactly once.
__global__ __launch_bounds__(256, 4) void k_main(const unsigned short* __restrict__ xb,
                                                 const int* __restrict__ tg,
                                                 float* __restrict__ bufP,
                                                 float* __restrict__ bufN) {
    __shared__ alignas(16) unsigned short As[128 * 64];
    __shared__ alignas(16) unsigned short Bs[128 * 64];
    __shared__ int rowT[128];

    const int tid  = threadIdx.x;
    const int w    = tid >> 6;
    const int lane = tid & 63;
    const int q    = lane >> 4;
    const int l15  = lane & 15;
    const int wrow = w >> 1;      // 0..1
    const int wcol = w & 1;       // 0..1

    // triangular decode: blockIdx.x -> (it, jt), it<=jt
    int rem = blockIdx.x;
    int it = 0;
    while (rem >= (T_ - it)) { rem -= (T_ - it); it++; }
    const int jt = it + rem;
    const int row0 = it * 128;
    const int col0 = jt * 128;

    if (tid < 128) rowT[tid] = tg[row0 + tid];
    __syncthreads();

    int tR[4][4];
#pragma unroll
    for (int mi = 0; mi < 4; ++mi)
#pragma unroll
        for (int r = 0; r < 4; ++r)
            tR[mi][r] = rowT[wrow * 64 + mi * 16 + q * 4 + r];

    int tC[4];
#pragma unroll
    for (int ni = 0; ni < 4; ++ni)
        tC[ni] = tg[col0 + wcol * 64 + ni * 16 + l15];

    f32x4 acc[4][4];
#pragma unroll
    for (int mi = 0; mi < 4; ++mi)
#pragma unroll
        for (int ni = 0; ni < 4; ++ni)
            acc[mi][ni] = (f32x4){0.f, 0.f, 0.f, 0.f};

    for (int ks = 0; ks < 8; ++ks) {
        const int k0 = ks * 64;
        __syncthreads();   // prior ds_reads done before restaging
        // stage A(128x64) and B(128x64): 4 wave-issues each, 16B/lane,
        // XOR-swizzled source so LDS slot s holds kgroup g = s ^ (row&7)
#pragma unroll
        for (int itr = 0; itr < 4; ++itr) {
            int gs = (itr * 4 + w) * 64 + lane;
            int r  = gs >> 3;
            int s  = gs & 7;
            int g  = s ^ (r & 7);
            const unsigned short* ga = xb + (size_t)(row0 + r) * D_ + k0 + g * 8;
            const unsigned short* gb = xb + (size_t)(col0 + r) * D_ + k0 + g * 8;
            __builtin_amdgcn_global_load_lds(
                (const __attribute__((address_space(1))) void*)ga,
                (__attribute__((address_space(3))) void*)(As + (itr * 4 + w) * 512),
                16, 0, 0);
            __builtin_amdgcn_global_load_lds(
                (const __attribute__((address_space(1))) void*)gb,
                (__attribute__((address_space(3))) void*)(Bs + (itr * 4 + w) * 512),
                16, 0, 0);
        }
        __syncthreads();   // barrier drains vmcnt -> LDS valid

#pragma unroll
        for (int kc = 0; kc < 2; ++kc) {
            bf16x8 aF[4], bF[4];
#pragma unroll
            for (int mi = 0; mi < 4; ++mi) {
                int rA = wrow * 64 + mi * 16 + l15;
                int g  = kc * 4 + q;
                int s  = g ^ (rA & 7);
                aF[mi] = *reinterpret_cast<const bf16x8*>(As + rA * 64 + s * 8);
            }
#pragma unroll
            for (int ni = 0; ni < 4; ++ni) {
                int rB = wcol * 64 + ni * 16 + l15;
                int g  = kc * 4 + q;
                int s  = g ^ (rB & 7);
                bF[ni] = *reinterpret_cast<const bf16x8*>(Bs + rB * 64 + s * 8);
            }
#pragma unroll
            for (int mi = 0; mi < 4; ++mi)
#pragma unroll
                for (int ni = 0; ni < 4; ++ni)
                    acc[mi][ni] = __builtin_amdgcn_mfma_f32_16x16x32_bf16(
                        aF[mi], bF[ni], acc[mi][ni], 0, 0, 0);
        }
    }

    // epilogue: single exp per element; row partials and (off-diag) col partials
    float ps[4][4], ns[4][4];
    float cps[4], cns[4];
#pragma unroll
    for (int mi = 0; mi < 4; ++mi)
#pragma unroll
        for (int r = 0; r < 4; ++r) { ps[mi][r] = 0.f; ns[mi][r] = 0.f; }
#pragma unroll
    for (int ni = 0; ni < 4; ++ni) { cps[ni] = 0.f; cns[ni] = 0.f; }

#pragma unroll
    for (int mi = 0; mi < 4; ++mi)
#pragma unroll
        for (int ni = 0; ni < 4; ++ni)
#pragma unroll
            for (int r = 0; r < 4; ++r) {
                float s = acc[mi][ni][r];
                bool same = (tR[mi][r] == tC[ni]);
                float e = __expf(same ? 1.0f - s : s);
                float pe = (same && (s < 1.0f)) ? e : 0.0f;
                float ne = same ? 0.0f : e;
                ps[mi][r] += pe; ns[mi][r] += ne;
                cps[ni]   += pe; cns[ni]   += ne;
            }

    // combine wave halves through LDS (reuse As), then coalesced global stores
    __syncthreads();                 // all ds_reads of As/Bs done
    float* scr = (float*)As;         // [0:256)=rowP, [256:512)=rowN,
                                     // [512:768)=colP, [768:1024)=colN

    // row partials: sum across the 16 lanes sharing a row
#pragma unroll
    for (int mi = 0; mi < 4; ++mi)
#pragma unroll
        for (int r = 0; r < 4; ++r) {
            float p = ps[mi][r];
            float n = ns[mi][r];
#pragma unroll
            for (int m = 1; m < 16; m <<= 1) {
                p += __shfl_xor(p, m, 64);
                n += __shfl_xor(n, m, 64);
            }
            if (l15 == 0) {
                int rloc = wrow * 64 + mi * 16 + q * 4 + r;
                scr[wcol * 128 + rloc]       = p;
                scr[256 + wcol * 128 + rloc] = n;
            }
        }

    // col partials: sum across q (lane bits 16,32)
#pragma unroll
    for (int ni = 0; ni < 4; ++ni) {
        float p = cps[ni];
        float n = cns[ni];
        p += __shfl_xor(p, 16, 64); p += __shfl_xor(p, 32, 64);
        n += __shfl_xor(n, 16, 64); n += __shfl_xor(n, 32, 64);
        if (q == 0) {
            int cloc = wcol * 64 + ni * 16 + l15;
            scr[512 + wrow * 128 + cloc] = p;
            scr[768 + wrow * 128 + cloc] = n;
        }
    }
    __syncthreads();

    if (tid < 128) {
        int r = tid;
        size_t off = ((size_t)it * T_ + jt) * 128 + r;
        bufP[off] = scr[r]       + scr[128 + r];
        bufN[off] = scr[256 + r] + scr[384 + r];
    } else if (jt != it) {
        int c = tid - 128;
        size_t off = ((size_t)jt * T_ + it) * 128 + c;
        bufP[off] = scr[512 + c] + scr[640 + c];
        bufN[off] = scr[768 + c] + scr[896 + c];
    }
}

// ---------- kernel 3: exact fp64 last-row dots -> sim_last[j] ----------
__global__ __launch_bounds__(256) void k_last(const float* __restrict__ x,
                                              double* __restrict__ sim_last) {
    int j    = (blockIdx.x * 256 + threadIdx.x) >> 6;
    int lane = threadIdx.x & 63;
    const float* xl = x + (size_t)(N_ - 1) * D_;
    const float* xj = x + (size_t)j * D_;
    double acc = 0.0;
#pragma unroll
    for (int it = 0; it < 8; ++it) {
        int k = it * 64 + lane;
        acc += (double)xl[k] * (double)xj[k];
    }
#pragma unroll
    for (int m = 32; m >= 1; m >>= 1) acc += __shfl_xor(acc, m, 64);
    if (lane == 0) sim_last[j] = acc;
}

// ---------- kernel 4: reduce partials -> psum/nsum (64 blocks, coalesced) ------
__global__ __launch_bounds__(256) void k_reduce(const float* __restrict__ bufP,
                                                const float* __restrict__ bufN,
                                                float* __restrict__ psum,
                                                float* __restrict__ nsum) {
    int t    = blockIdx.x;            // tile 0..63
    int half = threadIdx.x >> 7;      // 0: psum, 1: nsum
    int r    = threadIdx.x & 127;
    const float* buf = half ? bufN : bufP;
    const float* base = buf + (size_t)t * T_ * 128 + r;
    float s = 0.f;
#pragma unroll
    for (int o = 0; o < T_; ++o) s += base[o * 128];
    if (half) nsum[t * 128 + r] = s;
    else      psum[t * 128 + r] = s;
}

// ---------- kernel 5: finalize (single block, 1024 threads) ----------
__global__ __launch_bounds__(1024) void k_final(const float* __restrict__ psum,
                                                const float* __restrict__ nsum,
                                                const int* __restrict__ tg,
                                                const double* __restrict__ sim_last,
                                                float* __restrict__ out) {
    __shared__ int lh[NC_];
    __shared__ double sl[1024], sp[1024], sn[1024];
    __shared__ int    sk[1024], cp[1024], cn[1024];
    int tid = threadIdx.x;

    if (tid < NC_) lh[tid] = 0;
    __syncthreads();
    for (int i = tid; i < N_; i += 1024) atomicAdd(&lh[tg[i]], 1);
    __syncthreads();

    // loss + prec
    double part = 0.0;
    int skip = 0;
    for (int i = tid; i < N_; i += 1024) {
        if (lh[tg[i]] < N_) {
            part += (double)(logf(psum[i]) + logf(nsum[i]));
        } else {
            skip++;
        }
    }

    // last-row stats from sim_last
    double pd = 0.0, nd = 0.0;
    int pc = 0, nc = 0;
    int tlast = tg[N_ - 1];
    for (int j = tid; j < N_; j += 1024) {
        double s = sim_last[j];
        if (tg[j] == tlast) {
            if (s < 1.0) { pd += s; pc++; }
        } else {
            nd += s; nc++;
        }
    }

    sl[tid] = part; sk[tid] = skip;
    sp[tid] = pd;   cp[tid] = pc;
    sn[tid] = nd;   cn[tid] = nc;
    __syncthreads();
    for (int s = 512; s >= 1; s >>= 1) {
        if (tid < s) {
            sl[tid] += sl[tid + s]; sk[tid] += sk[tid + s];
            sp[tid] += sp[tid + s]; cp[tid] += cp[tid + s];
            sn[tid] += sn[tid + s]; cn[tid] += cn[tid + s];
        }
        __syncthreads();
    }
    if (tid == 0) {
        out[0] = (float)(sl[0] / (double)N_);
        out[1] = (float)sk[0] / (float)N_;
        out[2] = (float)(sp[0] / (double)cp[0]);
        out[3] = (float)(sn[0] / (double)cn[0]);
    }
}

extern "C" void kernel_launch(void* const* d_in, const int* in_sizes, int n_in,
                              void* d_out, int out_size, void* d_ws, size_t ws_size,
                              hipStream_t stream) {
    const float* x  = (const float*)d_in[0];
    const int*   tg = (const int*)d_in[1];
    char* ws = (char*)d_ws;

    unsigned short* xb = (unsigned short*)ws;            // 8 MB
    const size_t XB = (size_t)N_ * D_ * 2;               // 8388608
    float*  psum     = (float*)(ws + XB);                // 32 KB
    float*  nsum     = (float*)(ws + XB + 32768);        // 32 KB
    double* sim_last = (double*)(ws + XB + 65536);       // 64 KB
    float*  bufP     = (float*)(ws + XB + 131072);       // 64*64*128*4 = 2 MB
    float*  bufN     = (float*)(ws + XB + 131072 + 2097152); // 2 MB

    const int nblk_tri = T_ * (T_ + 1) / 2;              // 2080

    hipLaunchKernelGGL(k_convert, dim3((N_ * D_) / (256 * 4)), dim3(256), 0, stream, x, xb);
    hipLaunchKernelGGL(k_main, dim3(nblk_tri), dim3(256), 0, stream, xb, tg, bufP, bufN);
    hipLaunchKernelGGL(k_last, dim3((N_ * 64) / 256), dim3(256), 0, stream, x, sim_last);
    hipLaunchKernelGGL(k_reduce, dim3(T_), dim3(256), 0, stream, bufP, bufN, psum, nsum);
    hipLaunchKernelGGL(k_final, dim3(1), dim3(1024), 0, stream,
                       psum, nsum, tg, sim_last, (float*)d_out);
}